// Round 7
// baseline (182.447 us; speedup 1.0000x reference)
//
#include <hip/hip_runtime.h>
#include <math.h>

#define DDIM 2048
#define NEXP 64
#define BM 32            // (mono fallback tile)
#define BK 64
#define TOKB 64          // tokens per block (MFMA kernel)
#define CKM 64           // k-chunk staged in LDS
#define THETA 2e-5f      // bumped: bf16-split logit err ~4e-6 < fp32-era 1e-5 margin
#define MAXFLAG 16383
#define FLAGREGION 65536
#define WSPLITE (NEXP * DDIM)            // elements per W split plane
#define WSPLITB (WSPLITE * 2)            // bytes (bf16)

typedef __attribute__((ext_vector_type(8))) short bf16x8;
typedef __attribute__((ext_vector_type(4))) float f32x4;

// RNE f32->bf16 pair pack; returns packed u32 (lo=a, hi=b), outputs rounded f32
__device__ inline unsigned pkbf(float a, float b, float& fa, float& fb) {
    unsigned ba = __float_as_uint(a), bb = __float_as_uint(b);
    unsigned ra = (ba + 0x7fffu + ((ba >> 16) & 1u)) & 0xffff0000u;
    unsigned rb = (bb + 0x7fffu + ((bb >> 16) & 1u)) & 0xffff0000u;
    fa = __uint_as_float(ra); fb = __uint_as_float(rb);
    return (ra >> 16) | rb;
}

// ---------------------------------------------------------------------------
// Kernel 0: split W[64][2048] f32 -> Wh,Wl bf16 (same [e][k] layout; B-frags
// need k-contiguous rows, so NO transpose). 512 KB total, L2-resident.
// ---------------------------------------------------------------------------
__global__ void w_split(const float* __restrict__ W, ushort* __restrict__ Wh,
                        ushort* __restrict__ Wl) {
    const int gid = blockIdx.x * 256 + threadIdx.x;   // 32768 float4s
    const float4 v = ((const float4*)W)[gid];
    float h0, h1, h2, h3;
    unsigned H0 = pkbf(v.x, v.y, h0, h1);
    unsigned H1 = pkbf(v.z, v.w, h2, h3);
    float d0, d1, d2, d3;
    unsigned L0 = pkbf(v.x - h0, v.y - h1, d0, d1);
    unsigned L1 = pkbf(v.z - h2, v.w - h3, d2, d3);
    ((uint2*)Wh)[gid] = make_uint2(H0, H1);
    ((uint2*)Wl)[gid] = make_uint2(L0, L1);
}

// ---------------------------------------------------------------------------
// Kernel 1: MFMA gate. C[16384,64] = x * W^T via bf16-split 3-term MFMA
// (xh*wh + xh*wl + xl*wh), f32 accumulate. Fused sigmoid/top-7 epilogue.
// Wave w owns tokens [16w,16w+16) x all 64 experts (4 16x16x32 acc tiles).
// LDS octet-XOR swizzle: octet o of row r stored at o^(r&7) -> 2-way max
// on both fragment reads and staging writes.
// Escapes round-6's LDS-issue bound: 1 ds_read_b128 feeds 512 lane-FLOPs.
// ---------------------------------------------------------------------------
__launch_bounds__(256)
__global__ void gate_main(const float* __restrict__ x, const ushort* __restrict__ Wh,
                          const ushort* __restrict__ Wl, const float* __restrict__ gb,
                          float* __restrict__ out, int* __restrict__ wsc, int M) {
    __shared__ __align__(16) ushort xh[TOKB * CKM];   // 8 KB each
    __shared__ __align__(16) ushort xl[TOKB * CKM];
    __shared__ __align__(16) ushort wh[NEXP * CKM];
    __shared__ __align__(16) ushort wl[NEXP * CKM];
    __shared__ float sc[4][16][NEXP + 4];             // per-wave logit table

    const int tid = threadIdx.x;
    const int lane = tid & 63;
    const int w = tid >> 6;
    const int tok0 = blockIdx.x * TOKB;

    // staging role: row r (token or expert), k-sixteenth h -> octets 2h,2h+1
    const int r = tid >> 2;          // 0..63
    const int h = tid & 3;           // k offset 16*h
    const int o0 = (2 * h) ^ (r & 7);
    const int o1 = (2 * h + 1) ^ (r & 7);

    const float*  xsrc = x  + (size_t)(tok0 + r) * DDIM + 16 * h;
    const ushort* whs  = Wh + (size_t)r * DDIM + 16 * h;
    const ushort* wls  = Wl + (size_t)r * DDIM + 16 * h;

    f32x4 acc[4];
#pragma unroll
    for (int et = 0; et < 4; ++et) acc[et] = (f32x4){0.f, 0.f, 0.f, 0.f};

    // prefetch chunk 0
    float4 xr[4]; uint4 wrh[2], wrl[2];
#pragma unroll
    for (int q = 0; q < 4; ++q) xr[q] = *(const float4*)(xsrc + 4 * q);
    wrh[0] = *(const uint4*)(whs);  wrh[1] = *(const uint4*)(whs + 8);
    wrl[0] = *(const uint4*)(wls);  wrl[1] = *(const uint4*)(wls + 8);

    for (int c = 0; c < DDIM / CKM; ++c) {
        __syncthreads();   // prev chunk's LDS reads done
        // ---- convert + store x; store W (octet-swizzled b128 writes) ----
        {
            float h0,h1,h2,h3,h4,h5,h6,h7, d;
            uint4 H, L;
            H.x = pkbf(xr[0].x, xr[0].y, h0, h1);
            H.y = pkbf(xr[0].z, xr[0].w, h2, h3);
            H.z = pkbf(xr[1].x, xr[1].y, h4, h5);
            H.w = pkbf(xr[1].z, xr[1].w, h6, h7);
            L.x = pkbf(xr[0].x - h0, xr[0].y - h1, d, d);
            L.y = pkbf(xr[0].z - h2, xr[0].w - h3, d, d);
            L.z = pkbf(xr[1].x - h4, xr[1].y - h5, d, d);
            L.w = pkbf(xr[1].z - h6, xr[1].w - h7, d, d);
            *(uint4*)&xh[r * CKM + o0 * 8] = H;
            *(uint4*)&xl[r * CKM + o0 * 8] = L;
            H.x = pkbf(xr[2].x, xr[2].y, h0, h1);
            H.y = pkbf(xr[2].z, xr[2].w, h2, h3);
            H.z = pkbf(xr[3].x, xr[3].y, h4, h5);
            H.w = pkbf(xr[3].z, xr[3].w, h6, h7);
            L.x = pkbf(xr[2].x - h0, xr[2].y - h1, d, d);
            L.y = pkbf(xr[2].z - h2, xr[2].w - h3, d, d);
            L.z = pkbf(xr[3].x - h4, xr[3].y - h5, d, d);
            L.w = pkbf(xr[3].z - h6, xr[3].w - h7, d, d);
            *(uint4*)&xh[r * CKM + o1 * 8] = H;
            *(uint4*)&xl[r * CKM + o1 * 8] = L;
            *(uint4*)&wh[r * CKM + o0 * 8] = wrh[0];
            *(uint4*)&wh[r * CKM + o1 * 8] = wrh[1];
            *(uint4*)&wl[r * CKM + o0 * 8] = wrl[0];
            *(uint4*)&wl[r * CKM + o1 * 8] = wrl[1];
        }
        __syncthreads();
        // ---- prefetch next chunk ----
        if (c + 1 < DDIM / CKM) {
            const int kc = (c + 1) * CKM;
#pragma unroll
            for (int q = 0; q < 4; ++q) xr[q] = *(const float4*)(xsrc + kc + 4 * q);
            wrh[0] = *(const uint4*)(whs + kc);  wrh[1] = *(const uint4*)(whs + kc + 8);
            wrl[0] = *(const uint4*)(wls + kc);  wrl[1] = *(const uint4*)(wls + kc + 8);
        }
        // ---- compute: 2 k-steps of K=32; 12 MFMA per step per wave ----
#pragma unroll
        for (int ks = 0; ks < 2; ++ks) {
            const int oct = ks * 4 + (lane >> 4);
            const int rA = 16 * w + (lane & 15);
            const bf16x8 ah = *(const bf16x8*)&xh[rA * CKM + (oct ^ (rA & 7)) * 8];
            const bf16x8 al = *(const bf16x8*)&xl[rA * CKM + (oct ^ (rA & 7)) * 8];
#pragma unroll
            for (int et = 0; et < 4; ++et) {
                const int rB = 16 * et + (lane & 15);
                const bf16x8 bh = *(const bf16x8*)&wh[rB * CKM + (oct ^ (rB & 7)) * 8];
                const bf16x8 bl = *(const bf16x8*)&wl[rB * CKM + (oct ^ (rB & 7)) * 8];
                acc[et] = __builtin_amdgcn_mfma_f32_16x16x32_bf16(ah, bh, acc[et], 0, 0, 0);
                acc[et] = __builtin_amdgcn_mfma_f32_16x16x32_bf16(ah, bl, acc[et], 0, 0, 0);
                acc[et] = __builtin_amdgcn_mfma_f32_16x16x32_bf16(al, bh, acc[et], 0, 0, 0);
            }
        }
    }

    // ---- epilogue: scatter acc to per-wave logit table (wave-private) ----
#pragma unroll
    for (int et = 0; et < 4; ++et)
#pragma unroll
        for (int rg = 0; rg < 4; ++rg)
            sc[w][(lane >> 4) * 4 + rg][et * 16 + (lane & 15)] = acc[et][rg];
    // same-wave LDS RAW: compiler inserts lgkmcnt wait; no barrier needed.

    const float gbl = gb[lane];
    for (int tt = 0; tt < 16; ++tt) {
        const float lg = sc[w][tt][lane];
        const float sg = 1.f / (1.f + expf(-lg));
        float cur = sg + gbl;

        float vals[7]; int idxs[7]; float us[7];
#pragma unroll
        for (int p = 0; p < 7; ++p) {
            float v = cur; int id = lane;
#pragma unroll
            for (int o = 32; o > 0; o >>= 1) {
                const float ov = __shfl_xor(v, o, 64);
                const int oid = __shfl_xor(id, o, 64);
                const bool take = (ov > v) || (ov == v && oid < id);
                v = take ? ov : v;
                id = take ? oid : id;
            }
            vals[p] = v; idxs[p] = id;
            us[p] = __shfl(sg, id, 64);
            if (lane == id) cur = -1e30f;
        }

        if (lane == 0) {
            const int t = tok0 + 16 * w + tt;
            bool flag = false;
#pragma unroll
            for (int p = 0; p < 6; ++p) flag = flag || (vals[p] - vals[p + 1] < THETA);
            float sum = 0.f;
#pragma unroll
            for (int p = 0; p < 6; ++p) sum += us[p];
#pragma unroll
            for (int p = 0; p < 6; ++p)
                out[(size_t)t * 6 + p] = us[p] / sum * 2.5f;
            float* oi = out + (size_t)M * 6 + (size_t)t * 8;
            oi[0] = 0.f; oi[1] = 1.f;
#pragma unroll
            for (int p = 0; p < 6; ++p) oi[2 + p] = (float)(idxs[p] + 2);
            if (flag) {
                const int pos = atomicAdd(wsc, 1);
                if (pos < MAXFLAG) wsc[1 + pos] = t;
            }
        }
    }
}

// ---------------------------------------------------------------------------
// Kernel 2: f64 refine of flagged tokens (exact ordering). Unchanged.
// ---------------------------------------------------------------------------
__launch_bounds__(256, 2)
__global__ void gate_refine(const float* __restrict__ x, const float* __restrict__ W,
                            const float* __restrict__ gb, float* __restrict__ out,
                            const int* __restrict__ wsc, int M) {
    __shared__ double lg[NEXP];
    int cnt = wsc[0];
    if (cnt > MAXFLAG) cnt = MAXFLAG;
    const int wv = threadIdx.x >> 6;
    const int lane = threadIdx.x & 63;

    for (int i = blockIdx.x; i < cnt; i += gridDim.x) {
        const int t = wsc[1 + i];
        const float* xr = x + (size_t)t * DDIM;
        for (int ee = 0; ee < 16; ++ee) {
            const int e = wv * 16 + ee;
            const float* wr = W + (size_t)e * DDIM;
            double a0 = 0, a1 = 0, a2 = 0, a3 = 0;
#pragma unroll
            for (int it = 0; it < DDIM / 256; ++it) {
                const float4 xv = *(const float4*)(xr + it * 256 + lane * 4);
                const float4 wvv = *(const float4*)(wr + it * 256 + lane * 4);
                a0 = fma((double)xv.x, (double)wvv.x, a0);
                a1 = fma((double)xv.y, (double)wvv.y, a1);
                a2 = fma((double)xv.z, (double)wvv.z, a2);
                a3 = fma((double)xv.w, (double)wvv.w, a3);
            }
            double sd = (a0 + a1) + (a2 + a3);
#pragma unroll
            for (int o = 32; o > 0; o >>= 1) sd += __shfl_down(sd, o, 64);
            if (lane == 0) lg[e] = sd;
        }
        __syncthreads();
        if (threadIdx.x < NEXP) {
            const double l = lg[threadIdx.x];
            lg[threadIdx.x] = 1.0 / (1.0 + exp(-l)) + (double)gb[threadIdx.x];
        }
        __syncthreads();
        if (threadIdx.x == 0) {
            double val[7]; int idx[7];
#pragma unroll
            for (int p = 0; p < 7; ++p) { val[p] = -1e30; idx[p] = 0; }
            for (int e = 0; e < NEXP; ++e) {
                double v = lg[e]; int id = e;
#pragma unroll
                for (int p = 0; p < 7; ++p) {
                    const bool gt = v > val[p];
                    const double ov = val[p]; const int oi2 = idx[p];
                    val[p] = gt ? v : ov; idx[p] = gt ? id : oi2;
                    v = gt ? ov : v;      id = gt ? oi2 : id;
                }
            }
            double s6[6], sum = 0.0;
#pragma unroll
            for (int p = 0; p < 6; ++p) { s6[p] = val[p] - (double)gb[idx[p]]; sum += s6[p]; }
#pragma unroll
            for (int p = 0; p < 6; ++p)
                out[(size_t)t * 6 + p] = (float)(s6[p] / sum * 2.5);
            float* oi = out + (size_t)M * 6 + (size_t)t * 8;
            oi[0] = 0.f; oi[1] = 1.f;
#pragma unroll
            for (int p = 0; p < 6; ++p) oi[2 + p] = (float)(idx[p] + 2);
        }
        __syncthreads();
    }
}

// ---------------------------------------------------------------------------
// Fallback: monolithic vector kernel (used only if ws too small)
// ---------------------------------------------------------------------------
__launch_bounds__(256, 2)
__global__ void gate_mono(const float* __restrict__ x, const float* __restrict__ W,
                          const float* __restrict__ gb, float* __restrict__ out,
                          int* __restrict__ wsc, int M) {
    __shared__ __align__(16) float xs[BK * BM];
    __shared__ __align__(16) float wsh[BK * NEXP];

    const int tid = threadIdx.x;
    const int tg = tid & 15;
    const int eg = tid >> 4;
    const int tok0 = blockIdx.x * BM;
    const int sr = tid >> 3;
    const int sq = tid & 7;
    const float* xsrc  = x + (size_t)(tok0 + sr) * DDIM + 4 * sq;
    const float* wsrc0 = W + (size_t)sr * DDIM + 4 * sq;
    const float* wsrc1 = W + (size_t)(sr + 32) * DDIM + 4 * sq;

    int xoff[16], woff[16];
#pragma unroll
    for (int c = 0; c < 16; ++c) {
        xoff[c] = c * (BM * 4) + 8 * (tg ^ c);
        woff[c] = c * (NEXP * 4) + 16 * (eg ^ c);
    }
    float acc[2][4];
#pragma unroll
    for (int i = 0; i < 2; ++i)
#pragma unroll
        for (int j = 0; j < 4; ++j) acc[i][j] = 0.f;

    float4 px0 = *(const float4*)(xsrc);
    float4 px1 = *(const float4*)(xsrc + 32);
    float4 pw00 = *(const float4*)(wsrc0);
    float4 pw01 = *(const float4*)(wsrc0 + 32);
    float4 pw10 = *(const float4*)(wsrc1);
    float4 pw11 = *(const float4*)(wsrc1 + 32);

    for (int ch = 0; ch < DDIM / BK; ++ch) {
        __syncthreads();
#pragma unroll
        for (int m = 0; m < 4; ++m) {
            const int kkA = 4 * sq + m;
            const int kkB = kkA + 32;
            xs[kkA * BM + ((sr & 1) + 2 * ((sr >> 1) ^ (kkA & 15)))] = ((const float*)&px0)[m];
            xs[kkB * BM + ((sr & 1) + 2 * ((sr >> 1) ^ (kkB & 15)))] = ((const float*)&px1)[m];
            wsh[kkA * NEXP + ((sr & 3) + 4 * ((sr >> 2) ^ (kkA & 15)))] = ((const float*)&pw00)[m];
            wsh[kkB * NEXP + ((sr & 3) + 4 * ((sr >> 2) ^ (kkB & 15)))] = ((const float*)&pw01)[m];
            wsh[kkA * NEXP + (((sr + 32) & 3) + 4 * (((sr + 32) >> 2) ^ (kkA & 15)))] = ((const float*)&pw10)[m];
            wsh[kkB * NEXP + (((sr + 32) & 3) + 4 * (((sr + 32) >> 2) ^ (kkB & 15)))] = ((const float*)&pw11)[m];
        }
        __syncthreads();
        if (ch + 1 < DDIM / BK) {
            const int k0 = (ch + 1) * BK;
            px0 = *(const float4*)(xsrc + k0);
            px1 = *(const float4*)(xsrc + k0 + 32);
            pw00 = *(const float4*)(wsrc0 + k0);
            pw01 = *(const float4*)(wsrc0 + k0 + 32);
            pw10 = *(const float4*)(wsrc1 + k0);
            pw11 = *(const float4*)(wsrc1 + k0 + 32);
        }
        const char* xb = (const char*)xs;
        const char* wb = (const char*)wsh;
#pragma unroll
        for (int rep = 0; rep < 4; ++rep) {
#pragma unroll
            for (int c = 0; c < 16; ++c) {
                const float2 xv = *(const float2*)(xb + rep * (16 * BM * 4) + xoff[c]);
                const float4 wv = *(const float4*)(wb + rep * (16 * NEXP * 4) + woff[c]);
                acc[0][0] = fmaf(xv.x, wv.x, acc[0][0]);
                acc[0][1] = fmaf(xv.x, wv.y, acc[0][1]);
                acc[0][2] = fmaf(xv.x, wv.z, acc[0][2]);
                acc[0][3] = fmaf(xv.x, wv.w, acc[0][3]);
                acc[1][0] = fmaf(xv.y, wv.x, acc[1][0]);
                acc[1][1] = fmaf(xv.y, wv.y, acc[1][1]);
                acc[1][2] = fmaf(xv.y, wv.z, acc[1][2]);
                acc[1][3] = fmaf(xv.y, wv.w, acc[1][3]);
            }
        }
    }

    __syncthreads();
    float* sc = wsh;
#pragma unroll
    for (int i = 0; i < 2; ++i)
#pragma unroll
        for (int j = 0; j < 4; ++j)
            sc[(2 * tg + i) * 68 + (4 * eg + j)] = acc[i][j];
    __syncthreads();

    if (tid < BM) {
        const int t = tok0 + tid;
        float val[7]; int idx[7];
#pragma unroll
        for (int p = 0; p < 7; ++p) { val[p] = -1e30f; idx[p] = 0; }
        for (int e = 0; e < NEXP; ++e) {
            const float l = sc[tid * 68 + e];
            const float sg = 1.f / (1.f + expf(-l));
            float v = sg + gb[e];
            int id = e;
#pragma unroll
            for (int p = 0; p < 7; ++p) {
                const bool gt = v > val[p];
                const float ov = val[p]; const int oi = idx[p];
                val[p] = gt ? v : ov;  idx[p] = gt ? id : oi;
                v = gt ? ov : v;       id = gt ? oi : id;
            }
        }
        bool flag = false;
#pragma unroll
        for (int p = 0; p < 6; ++p) flag = flag || (val[p] - val[p + 1] < THETA);

        float s6[6]; float sum = 0.f;
#pragma unroll
        for (int p = 0; p < 6; ++p) {
            const float l = sc[tid * 68 + idx[p]];
            s6[p] = 1.f / (1.f + expf(-l));
            sum += s6[p];
        }
#pragma unroll
        for (int p = 0; p < 6; ++p)
            out[(size_t)t * 6 + p] = s6[p] / sum * 2.5f;

        float* oi = out + (size_t)M * 6 + (size_t)t * 8;
        oi[0] = 0.f; oi[1] = 1.f;
#pragma unroll
        for (int p = 0; p < 6; ++p) oi[2 + p] = (float)(idx[p] + 2);

        if (flag && wsc) {
            const int pos = atomicAdd(wsc, 1);
            if (pos < MAXFLAG) wsc[1 + pos] = t;
        }
    }
}

extern "C" void kernel_launch(void* const* d_in, const int* in_sizes, int n_in,
                              void* d_out, int out_size, void* d_ws, size_t ws_size,
                              hipStream_t stream) {
    const float* x = (const float*)d_in[0];
    const float* W = (const float*)d_in[1];
    const float* gb = (const float*)d_in[2];
    float* out = (float*)d_out;
    const int M = in_sizes[0] / DDIM;   // 16384

    // ws layout: [flags 64KB | Wh 256KB | Wl 256KB]
    const size_t need = (size_t)FLAGREGION + 2 * (size_t)WSPLITB;

    if (ws_size >= need) {
        int* wsc = (int*)d_ws;
        ushort* Wh = (ushort*)((char*)d_ws + FLAGREGION);
        ushort* Wl = Wh + WSPLITE;
        hipMemsetAsync(d_ws, 0, sizeof(int), stream);
        hipLaunchKernelGGL(w_split, dim3(WSPLITE / 4 / 256), dim3(256), 0, stream,
                           W, Wh, Wl);
        hipLaunchKernelGGL(gate_main, dim3(M / TOKB), dim3(256), 0, stream,
                           x, Wh, Wl, gb, out, wsc, M);
        hipLaunchKernelGGL(gate_refine, dim3(256), dim3(256), 0, stream,
                           x, W, gb, out, wsc, M);
    } else {
        const bool refine_ok = ws_size >= (size_t)(1 + MAXFLAG) * sizeof(int);
        int* wsc = refine_ok ? (int*)d_ws : (int*)nullptr;
        if (refine_ok) hipMemsetAsync(d_ws, 0, sizeof(int), stream);
        hipLaunchKernelGGL(gate_mono, dim3(M / BM), dim3(256), 0, stream,
                           x, W, gb, out, wsc, M);
        if (refine_ok)
            hipLaunchKernelGGL(gate_refine, dim3(256), dim3(256), 0, stream,
                               x, W, gb, out, wsc, M);
    }
}

// Round 8
// 138.707 us; speedup vs baseline: 1.3153x; 1.3153x over previous
//
#include <hip/hip_runtime.h>
#include <math.h>

#define DDIM 2048
#define NEXP 64
#define BM 32            // (mono fallback tile)
#define BK 64
#define TOKB 16          // tokens per block (MFMA kernel) -> grid 1024 = 4 blk/CU
#define CKM 128          // k-chunk staged in LDS
#define THETA 2e-5f      // bf16-split logit err ~4e-6 << theta
#define MAXFLAG 16383
#define FLAGREGION 65536
#define WSPLITE (NEXP * DDIM)            // elements per W split plane
#define WSPLITB (WSPLITE * 2)            // bytes (bf16)

typedef __attribute__((ext_vector_type(8))) short bf16x8;
typedef __attribute__((ext_vector_type(4))) float f32x4;

// RNE f32->bf16 pair pack; returns packed u32 (lo=a, hi=b), outputs rounded f32
__device__ inline unsigned pkbf(float a, float b, float& fa, float& fb) {
    unsigned ba = __float_as_uint(a), bb = __float_as_uint(b);
    unsigned ra = (ba + 0x7fffu + ((ba >> 16) & 1u)) & 0xffff0000u;
    unsigned rb = (bb + 0x7fffu + ((bb >> 16) & 1u)) & 0xffff0000u;
    fa = __uint_as_float(ra); fb = __uint_as_float(rb);
    return (ra >> 16) | rb;
}

// ---------------------------------------------------------------------------
// Kernel 0: split W[64][2048] f32 -> Wh,Wl bf16 (row-major [e][k]; B-frags
// read k-contiguous 16B runs per expert row). 512 KB total, L2-resident.
// ---------------------------------------------------------------------------
__global__ void w_split(const float* __restrict__ W, ushort* __restrict__ Wh,
                        ushort* __restrict__ Wl) {
    const int gid = blockIdx.x * 256 + threadIdx.x;   // 32768 float4s
    const float4 v = ((const float4*)W)[gid];
    float h0, h1, h2, h3;
    unsigned H0 = pkbf(v.x, v.y, h0, h1);
    unsigned H1 = pkbf(v.z, v.w, h2, h3);
    float d0, d1, d2, d3;
    unsigned L0 = pkbf(v.x - h0, v.y - h1, d0, d1);
    unsigned L1 = pkbf(v.z - h2, v.w - h3, d2, d3);
    ((uint2*)Wh)[gid] = make_uint2(H0, H1);
    ((uint2*)Wl)[gid] = make_uint2(L0, L1);
}

// ---------------------------------------------------------------------------
// Kernel 1: MFMA gate, EXPERT-SPLIT waves. Wave w: all 16 block tokens x
// experts [16w,16w+16) = ONE 16x16x32 acc tile, 3-term bf16 split.
// Round-7 failure: TOKB=64 -> grid 256 = 1 block/CU = 11% occupancy,
// 125us of uncovered latency. Now grid 1024 (4 blk/CU, 16 waves/CU).
// x: staged in LDS once per block (bf16-split, octet-XOR swizzle; R7 scheme
// measured 0 conflicts), shared by all 4 waves. W: b128 frags loaded DIRECTLY
// from L2-hot Wh/Wl (no LDS staging). Fragment lane-maps verified by R7 pass.
// ---------------------------------------------------------------------------
__launch_bounds__(256)
__global__ void gate_main(const float* __restrict__ x, const ushort* __restrict__ Wh,
                          const ushort* __restrict__ Wl, const float* __restrict__ gb,
                          float* __restrict__ out, int* __restrict__ wsc, int M) {
    __shared__ __align__(16) ushort xh[TOKB * CKM];   // 4 KB each, group-swizzled
    __shared__ __align__(16) ushort xl[TOKB * CKM];
    __shared__ float sc[TOKB][NEXP + 4];              // logit table (4.3 KB)

    const int tid = threadIdx.x;
    const int lane = tid & 63;
    const int w = tid >> 6;
    const int tok0 = blockIdx.x * TOKB;

    // staging role: token r (0..15), k-octet g (0..15); 8 f32 -> 8 bf16 pairs
    const int r = tid >> 4;
    const int g = tid & 15;
    const int colg = (g & 8) | ((g & 7) ^ (r & 7));   // XOR swizzle on low 3 bits
    const float* xsrc = x + (size_t)(tok0 + r) * DDIM + 8 * g;
    ushort* xhw = &xh[r * CKM + colg * 8];
    ushort* xlw = &xl[r * CKM + colg * 8];

    // compute-side roles
    const int tA = lane & 15;        // A row (token) / B row offset (expert)
    const int ks8 = lane >> 4;       // k-slot 0..3
    const ushort* whb = Wh + (size_t)(16 * w + tA) * DDIM + 8 * ks8;
    const ushort* wlb = Wl + (size_t)(16 * w + tA) * DDIM + 8 * ks8;

    f32x4 acc = (f32x4){0.f, 0.f, 0.f, 0.f};

    // prologue: prefetch chunk 0 x (2 float4 = 8 f32 per thread)
    float4 xr0 = *(const float4*)(xsrc);
    float4 xr1 = *(const float4*)(xsrc + 4);

    for (int c = 0; c < DDIM / CKM; ++c) {
        const int kk = c * CKM;
        // W frags for this chunk (4 ksteps x bh/bl); independent of barriers,
        // vmcnt-waited at first MFMA use -> overlaps staging.
        uint4 bhf[4], blf[4];
#pragma unroll
        for (int ks = 0; ks < 4; ++ks) {
            bhf[ks] = *(const uint4*)(whb + kk + 32 * ks);
            blf[ks] = *(const uint4*)(wlb + kk + 32 * ks);
        }
        __syncthreads();   // prev chunk's LDS reads done
        // ---- convert + store x chunk (swizzled b128 writes) ----
        {
            float h0, h1, h2, h3, h4, h5, h6, h7, d;
            uint4 H, L;
            H.x = pkbf(xr0.x, xr0.y, h0, h1);
            H.y = pkbf(xr0.z, xr0.w, h2, h3);
            H.z = pkbf(xr1.x, xr1.y, h4, h5);
            H.w = pkbf(xr1.z, xr1.w, h6, h7);
            L.x = pkbf(xr0.x - h0, xr0.y - h1, d, d);
            L.y = pkbf(xr0.z - h2, xr0.w - h3, d, d);
            L.z = pkbf(xr1.x - h4, xr1.y - h5, d, d);
            L.w = pkbf(xr1.z - h6, xr1.w - h7, d, d);
            *(uint4*)xhw = H;
            *(uint4*)xlw = L;
        }
        __syncthreads();
        // ---- prefetch next x chunk ----
        if (c + 1 < DDIM / CKM) {
            xr0 = *(const float4*)(xsrc + (c + 1) * CKM);
            xr1 = *(const float4*)(xsrc + (c + 1) * CKM + 4);
        }
        // ---- compute: 4 ksteps of K=32, 3 MFMA each ----
#pragma unroll
        for (int ks = 0; ks < 4; ++ks) {
            const int gidx = ks * 4 + ks8;
            const int col = (gidx & 8) | ((gidx & 7) ^ (tA & 7));
            const bf16x8 ah = *(const bf16x8*)&xh[tA * CKM + col * 8];
            const bf16x8 al = *(const bf16x8*)&xl[tA * CKM + col * 8];
            const bf16x8 bh = *(const bf16x8*)&bhf[ks];
            const bf16x8 bl = *(const bf16x8*)&blf[ks];
            acc = __builtin_amdgcn_mfma_f32_16x16x32_bf16(ah, bh, acc, 0, 0, 0);
            acc = __builtin_amdgcn_mfma_f32_16x16x32_bf16(ah, bl, acc, 0, 0, 0);
            acc = __builtin_amdgcn_mfma_f32_16x16x32_bf16(al, bh, acc, 0, 0, 0);
        }
    }

    // ---- epilogue: gather logits cross-wave, then 4 tokens per wave ----
#pragma unroll
    for (int rg = 0; rg < 4; ++rg)
        sc[(lane >> 4) * 4 + rg][16 * w + tA] = acc[rg];   // C-map verified (R7)
    __syncthreads();

    const float gbl = gb[lane];
    for (int tt = 4 * w; tt < 4 * w + 4; ++tt) {
        const float lg = sc[tt][lane];
        const float sg = 1.f / (1.f + expf(-lg));
        float cur = sg + gbl;

        float vals[7]; int idxs[7]; float us[7];
#pragma unroll
        for (int p = 0; p < 7; ++p) {
            float v = cur; int id = lane;
#pragma unroll
            for (int o = 32; o > 0; o >>= 1) {   // butterfly argmax, tie->low idx
                const float ov = __shfl_xor(v, o, 64);
                const int oid = __shfl_xor(id, o, 64);
                const bool take = (ov > v) || (ov == v && oid < id);
                v = take ? ov : v;
                id = take ? oid : id;
            }
            vals[p] = v; idxs[p] = id;
            us[p] = __shfl(sg, id, 64);
            if (lane == id) cur = -1e30f;
        }

        if (lane == 0) {
            const int t = tok0 + tt;
            bool flag = false;
#pragma unroll
            for (int p = 0; p < 6; ++p) flag = flag || (vals[p] - vals[p + 1] < THETA);
            float sum = 0.f;
#pragma unroll
            for (int p = 0; p < 6; ++p) sum += us[p];
#pragma unroll
            for (int p = 0; p < 6; ++p)
                out[(size_t)t * 6 + p] = us[p] / sum * 2.5f;
            float* oi = out + (size_t)M * 6 + (size_t)t * 8;
            oi[0] = 0.f; oi[1] = 1.f;
#pragma unroll
            for (int p = 0; p < 6; ++p) oi[2 + p] = (float)(idxs[p] + 2);
            if (flag) {
                const int pos = atomicAdd(wsc, 1);
                if (pos < MAXFLAG) wsc[1 + pos] = t;
            }
        }
    }
}

// ---------------------------------------------------------------------------
// Kernel 2: f64 refine of flagged tokens (exact ordering). Unchanged.
// ---------------------------------------------------------------------------
__launch_bounds__(256, 2)
__global__ void gate_refine(const float* __restrict__ x, const float* __restrict__ W,
                            const float* __restrict__ gb, float* __restrict__ out,
                            const int* __restrict__ wsc, int M) {
    __shared__ double lg[NEXP];
    int cnt = wsc[0];
    if (cnt > MAXFLAG) cnt = MAXFLAG;
    const int wv = threadIdx.x >> 6;
    const int lane = threadIdx.x & 63;

    for (int i = blockIdx.x; i < cnt; i += gridDim.x) {
        const int t = wsc[1 + i];
        const float* xr = x + (size_t)t * DDIM;
        for (int ee = 0; ee < 16; ++ee) {
            const int e = wv * 16 + ee;
            const float* wr = W + (size_t)e * DDIM;
            double a0 = 0, a1 = 0, a2 = 0, a3 = 0;
#pragma unroll
            for (int it = 0; it < DDIM / 256; ++it) {
                const float4 xv = *(const float4*)(xr + it * 256 + lane * 4);
                const float4 wvv = *(const float4*)(wr + it * 256 + lane * 4);
                a0 = fma((double)xv.x, (double)wvv.x, a0);
                a1 = fma((double)xv.y, (double)wvv.y, a1);
                a2 = fma((double)xv.z, (double)wvv.z, a2);
                a3 = fma((double)xv.w, (double)wvv.w, a3);
            }
            double sd = (a0 + a1) + (a2 + a3);
#pragma unroll
            for (int o = 32; o > 0; o >>= 1) sd += __shfl_down(sd, o, 64);
            if (lane == 0) lg[e] = sd;
        }
        __syncthreads();
        if (threadIdx.x < NEXP) {
            const double l = lg[threadIdx.x];
            lg[threadIdx.x] = 1.0 / (1.0 + exp(-l)) + (double)gb[threadIdx.x];
        }
        __syncthreads();
        if (threadIdx.x == 0) {
            double val[7]; int idx[7];
#pragma unroll
            for (int p = 0; p < 7; ++p) { val[p] = -1e30; idx[p] = 0; }
            for (int e = 0; e < NEXP; ++e) {
                double v = lg[e]; int id = e;
#pragma unroll
                for (int p = 0; p < 7; ++p) {
                    const bool gt = v > val[p];
                    const double ov = val[p]; const int oi2 = idx[p];
                    val[p] = gt ? v : ov; idx[p] = gt ? id : oi2;
                    v = gt ? ov : v;      id = gt ? oi2 : id;
                }
            }
            double s6[6], sum = 0.0;
#pragma unroll
            for (int p = 0; p < 6; ++p) { s6[p] = val[p] - (double)gb[idx[p]]; sum += s6[p]; }
#pragma unroll
            for (int p = 0; p < 6; ++p)
                out[(size_t)t * 6 + p] = (float)(s6[p] / sum * 2.5);
            float* oi = out + (size_t)M * 6 + (size_t)t * 8;
            oi[0] = 0.f; oi[1] = 1.f;
#pragma unroll
            for (int p = 0; p < 6; ++p) oi[2 + p] = (float)(idx[p] + 2);
        }
        __syncthreads();
    }
}

// ---------------------------------------------------------------------------
// Fallback: monolithic vector kernel (used only if ws too small)
// ---------------------------------------------------------------------------
__launch_bounds__(256, 2)
__global__ void gate_mono(const float* __restrict__ x, const float* __restrict__ W,
                          const float* __restrict__ gb, float* __restrict__ out,
                          int* __restrict__ wsc, int M) {
    __shared__ __align__(16) float xs[BK * BM];
    __shared__ __align__(16) float wsh[BK * NEXP];

    const int tid = threadIdx.x;
    const int tg = tid & 15;
    const int eg = tid >> 4;
    const int tok0 = blockIdx.x * BM;
    const int sr = tid >> 3;
    const int sq = tid & 7;
    const float* xsrc  = x + (size_t)(tok0 + sr) * DDIM + 4 * sq;
    const float* wsrc0 = W + (size_t)sr * DDIM + 4 * sq;
    const float* wsrc1 = W + (size_t)(sr + 32) * DDIM + 4 * sq;

    int xoff[16], woff[16];
#pragma unroll
    for (int c = 0; c < 16; ++c) {
        xoff[c] = c * (BM * 4) + 8 * (tg ^ c);
        woff[c] = c * (NEXP * 4) + 16 * (eg ^ c);
    }
    float acc[2][4];
#pragma unroll
    for (int i = 0; i < 2; ++i)
#pragma unroll
        for (int j = 0; j < 4; ++j) acc[i][j] = 0.f;

    float4 px0 = *(const float4*)(xsrc);
    float4 px1 = *(const float4*)(xsrc + 32);
    float4 pw00 = *(const float4*)(wsrc0);
    float4 pw01 = *(const float4*)(wsrc0 + 32);
    float4 pw10 = *(const float4*)(wsrc1);
    float4 pw11 = *(const float4*)(wsrc1 + 32);

    for (int ch = 0; ch < DDIM / BK; ++ch) {
        __syncthreads();
#pragma unroll
        for (int m = 0; m < 4; ++m) {
            const int kkA = 4 * sq + m;
            const int kkB = kkA + 32;
            xs[kkA * BM + ((sr & 1) + 2 * ((sr >> 1) ^ (kkA & 15)))] = ((const float*)&px0)[m];
            xs[kkB * BM + ((sr & 1) + 2 * ((sr >> 1) ^ (kkB & 15)))] = ((const float*)&px1)[m];
            wsh[kkA * NEXP + ((sr & 3) + 4 * ((sr >> 2) ^ (kkA & 15)))] = ((const float*)&pw00)[m];
            wsh[kkB * NEXP + ((sr & 3) + 4 * ((sr >> 2) ^ (kkB & 15)))] = ((const float*)&pw01)[m];
            wsh[kkA * NEXP + (((sr + 32) & 3) + 4 * (((sr + 32) >> 2) ^ (kkA & 15)))] = ((const float*)&pw10)[m];
            wsh[kkB * NEXP + (((sr + 32) & 3) + 4 * (((sr + 32) >> 2) ^ (kkB & 15)))] = ((const float*)&pw11)[m];
        }
        __syncthreads();
        if (ch + 1 < DDIM / BK) {
            const int k0 = (ch + 1) * BK;
            px0 = *(const float4*)(xsrc + k0);
            px1 = *(const float4*)(xsrc + k0 + 32);
            pw00 = *(const float4*)(wsrc0 + k0);
            pw01 = *(const float4*)(wsrc0 + k0 + 32);
            pw10 = *(const float4*)(wsrc1 + k0);
            pw11 = *(const float4*)(wsrc1 + k0 + 32);
        }
        const char* xb = (const char*)xs;
        const char* wb = (const char*)wsh;
#pragma unroll
        for (int rep = 0; rep < 4; ++rep) {
#pragma unroll
            for (int c = 0; c < 16; ++c) {
                const float2 xv = *(const float2*)(xb + rep * (16 * BM * 4) + xoff[c]);
                const float4 wv = *(const float4*)(wb + rep * (16 * NEXP * 4) + woff[c]);
                acc[0][0] = fmaf(xv.x, wv.x, acc[0][0]);
                acc[0][1] = fmaf(xv.x, wv.y, acc[0][1]);
                acc[0][2] = fmaf(xv.x, wv.z, acc[0][2]);
                acc[0][3] = fmaf(xv.x, wv.w, acc[0][3]);
                acc[1][0] = fmaf(xv.y, wv.x, acc[1][0]);
                acc[1][1] = fmaf(xv.y, wv.y, acc[1][1]);
                acc[1][2] = fmaf(xv.y, wv.z, acc[1][2]);
                acc[1][3] = fmaf(xv.y, wv.w, acc[1][3]);
            }
        }
    }

    __syncthreads();
    float* sc = wsh;
#pragma unroll
    for (int i = 0; i < 2; ++i)
#pragma unroll
        for (int j = 0; j < 4; ++j)
            sc[(2 * tg + i) * 68 + (4 * eg + j)] = acc[i][j];
    __syncthreads();

    if (tid < BM) {
        const int t = tok0 + tid;
        float val[7]; int idx[7];
#pragma unroll
        for (int p = 0; p < 7; ++p) { val[p] = -1e30f; idx[p] = 0; }
        for (int e = 0; e < NEXP; ++e) {
            const float l = sc[tid * 68 + e];
            const float sg = 1.f / (1.f + expf(-l));
            float v = sg + gb[e];
            int id = e;
#pragma unroll
            for (int p = 0; p < 7; ++p) {
                const bool gt = v > val[p];
                const float ov = val[p]; const int oi = idx[p];
                val[p] = gt ? v : ov;  idx[p] = gt ? id : oi;
                v = gt ? ov : v;       id = gt ? oi : id;
            }
        }
        bool flag = false;
#pragma unroll
        for (int p = 0; p < 6; ++p) flag = flag || (val[p] - val[p + 1] < THETA);

        float s6[6]; float sum = 0.f;
#pragma unroll
        for (int p = 0; p < 6; ++p) {
            const float l = sc[tid * 68 + idx[p]];
            s6[p] = 1.f / (1.f + expf(-l));
            sum += s6[p];
        }
#pragma unroll
        for (int p = 0; p < 6; ++p)
            out[(size_t)t * 6 + p] = s6[p] / sum * 2.5f;

        float* oi = out + (size_t)M * 6 + (size_t)t * 8;
        oi[0] = 0.f; oi[1] = 1.f;
#pragma unroll
        for (int p = 0; p < 6; ++p) oi[2 + p] = (float)(idx[p] + 2);

        if (flag && wsc) {
            const int pos = atomicAdd(wsc, 1);
            if (pos < MAXFLAG) wsc[1 + pos] = t;
        }
    }
}

extern "C" void kernel_launch(void* const* d_in, const int* in_sizes, int n_in,
                              void* d_out, int out_size, void* d_ws, size_t ws_size,
                              hipStream_t stream) {
    const float* x = (const float*)d_in[0];
    const float* W = (const float*)d_in[1];
    const float* gb = (const float*)d_in[2];
    float* out = (float*)d_out;
    const int M = in_sizes[0] / DDIM;   // 16384

    // ws layout: [flags 64KB | Wh 256KB | Wl 256KB]
    const size_t need = (size_t)FLAGREGION + 2 * (size_t)WSPLITB;

    if (ws_size >= need) {
        int* wsc = (int*)d_ws;
        ushort* Wh = (ushort*)((char*)d_ws + FLAGREGION);
        ushort* Wl = Wh + WSPLITE;
        hipMemsetAsync(d_ws, 0, sizeof(int), stream);
        hipLaunchKernelGGL(w_split, dim3(WSPLITE / 4 / 256), dim3(256), 0, stream,
                           W, Wh, Wl);
        hipLaunchKernelGGL(gate_main, dim3(M / TOKB), dim3(256), 0, stream,
                           x, Wh, Wl, gb, out, wsc, M);
        hipLaunchKernelGGL(gate_refine, dim3(256), dim3(256), 0, stream,
                           x, W, gb, out, wsc, M);
    } else {
        const bool refine_ok = ws_size >= (size_t)(1 + MAXFLAG) * sizeof(int);
        int* wsc = refine_ok ? (int*)d_ws : (int*)nullptr;
        if (refine_ok) hipMemsetAsync(d_ws, 0, sizeof(int), stream);
        hipLaunchKernelGGL(gate_mono, dim3(M / BM), dim3(256), 0, stream,
                           x, W, gb, out, wsc, M);
        if (refine_ok)
            hipLaunchKernelGGL(gate_refine, dim3(256), dim3(256), 0, stream,
                               x, W, gb, out, wsc, M);
    }
}